// Round 3
// baseline (746.322 us; speedup 1.0000x reference)
//
#include <hip/hip_runtime.h>
#include <hip/hip_fp16.h>
#include <stdint.h>

// Linear4bit: out[t,n] = (sum_k a4[t,k]*w4[n,k]) * sx[t] * sw[n], fp16-rounded.
// Inputs arrive int32-widened: one int32 per *packed byte* (two nibbles).
// Round-9: LDS-bandwidth theory. gemm_i8_sq: 256x256 block, 4 waves of
// 128x128 (acc[4][4]=256 regs, 1 wave/SIMD), LDS read drops 0.75->0.5 KB/MFMA
// (64 ds_read_b128 + 32KB DMA-write per block-stage ~1090cy < 1170cy matrix
// window). 4-buffer distance-3 DMA, uniform vmcnt(8); cross-stage k0-fragment
// preload so MFMA operands are in regs when each barrier opens. Bijective XCD
// swizzle (688%8==0). A workspace re-laid to 256-row panels (same k-perm).

#define T_DIM 4096
#define K_DIM 4096
#define N_DIM 11008
#define KP    2048              // packed bytes (= int32 elements) per row
#define STAGES 64               // BK = 64 (32 packed bytes per row per stage)
// --- i8 path geometry (round-9) ---
#define BM2 256
#define BN2 256
#define CHUNK2 16384            // 4 cells x 256 rows x 16B (A and B identical)
#define A_PANELS2 (T_DIM / BM2)   // 16
#define B_PANELS2 (N_DIM / BN2)   // 43
#define NWG2 (A_PANELS2 * B_PANELS2)      // 688, divisible by 8
#define CPX2 (NWG2 / 8)                   // 86 blocks per XCD
// --- workspace sizes (unchanged byte totals) ---
#define WS_A ((size_t)A_PANELS2 * STAGES * CHUNK2)   // 16,777,216
#define WS_B ((size_t)B_PANELS2 * STAGES * CHUNK2)   // 45,088,768
#define NA_BYTES ((size_t)T_DIM * KP)                // fallback packed sizes
#define NW_BYTES ((size_t)N_DIM * KP)

typedef __attribute__((ext_vector_type(4)))  int int32x4;
typedef __attribute__((ext_vector_type(16))) int int32x16;
typedef __attribute__((ext_vector_type(4)))  float floatx4;
typedef __attribute__((ext_vector_type(8)))  _Float16 f16x8;
typedef __attribute__((ext_vector_type(2)))  _Float16 f16x2;

__device__ __forceinline__ uint32_t pack4(int4 v) {
  return (uint32_t)(v.x & 0xFF) | ((uint32_t)(v.y & 0xFF) << 8) |
         ((uint32_t)(v.z & 0xFF) << 16) | ((uint32_t)(v.w & 0xFF) << 24);
}
// borrow-free SWAR nibble -> signed int8
__device__ __forceinline__ uint32_t nib_lo_s8(uint32_t p) {
  uint32_t t = (p & 0x0F0F0F0Fu) ^ 0x88888888u;
  return (t - 0x08080808u) ^ 0x80808080u;
}
__device__ __forceinline__ uint32_t nib_hi_s8(uint32_t p) {
  uint32_t t = ((p >> 4) & 0x0F0F0F0Fu) ^ 0x88888888u;
  return (t - 0x08080808u) ^ 0x80808080u;
}

// ------------- preprocess v4: coalesced loads + LDS transpose -------------
// Identical algorithm to round-8's unpack_tiles3; A panels are now 256 rows
// (same mapping as B). k-permutation per (row,stage) unchanged and identical
// for A and B => MFMA dot product unaffected.
#define ROWS_PB 32
#define SGRP    16

__global__ __launch_bounds__(256) void unpack_tiles4(
    const int* __restrict__ xa, const int* __restrict__ xw,
    uint8_t* __restrict__ wsa, uint8_t* __restrict__ wsb)
{
  __shared__ __align__(16) uint32_t lds[8192];   // 32 KB
  const int sg  = blockIdx.x;        // stage group 0..3 (16 stages each)
  const int yb  = blockIdx.y;        // A: [0,128)  B: [128,472)
  const int tid = threadIdx.x;

  const int* srcBase; uint8_t* dstBase;
  if (yb < T_DIM / ROWS_PB) {
    srcBase = xa + (size_t)yb * ROWS_PB * KP + sg * SGRP * 32;
    dstBase = wsa + ((size_t)(yb >> 3) * STAGES + sg * SGRP) * CHUNK2
                  + (size_t)(yb & 7) * (ROWS_PB * 16);
  } else {
    const int zb = yb - T_DIM / ROWS_PB;         // 0..343
    srcBase = xw + (size_t)zb * ROWS_PB * KP + sg * SGRP * 32;
    dstBase = wsb + ((size_t)(zb >> 3) * STAGES + sg * SGRP) * CHUNK2
                  + (size_t)(zb & 7) * (ROWS_PB * 16);
  }

  // ---- phase 1: global (coalesced) -> LDS (swizzled) ----
  const int lq    = tid & 127;       // 128 threads cover one 2KB row-slice
  const int rhalf = tid >> 7;        // which of the 2 rows per iteration
  const int sl    = lq >> 3;         // stage-local 0..15
  const int tg    = lq & 7;          // byte-group 0..7 (4 packed bytes each)
  const int cellL = (tg & 1) * 2;
  const int dsl   = tg >> 1;         // dword slot 0..3
#pragma unroll
  for (int it = 0; it < 16; ++it) {
    const int row = it * 2 + rhalf;
    const int4 v = *(const int4*)(srcBase + (size_t)row * KP + lq * 4);
    const uint32_t p = pack4(v);
    const int sp = sl ^ (row & 7);
    uint32_t* b = &lds[(((cellL * 32 + row) << 4) + sp) * 4 + dsl];
    b[0]    = nib_lo_s8(p);          // cell cellL
    b[2048] = nib_hi_s8(p);          // cell cellL+1  (+32*16*4 dwords)
  }
  __syncthreads();

  // ---- phase 2: LDS -> workspace, 512B contiguous runs per half-wave ----
  const int row2 = tid & 31;
#pragma unroll
  for (int it = 0; it < 8; ++it) {
    const int pr = it * 8 + (tid >> 5);          // 0..63 = (stage,cell) pair
    const int s2 = pr >> 2, cl = pr & 3;
    const int sp = s2 ^ (row2 & 7);
    const uint4 v = *(const uint4*)&lds[(((cl * 32 + row2) << 4) + sp) * 4];
    *(uint4*)(dstBase + (size_t)s2 * CHUNK2 + cl * 4096 + row2 * 16) = v;
  }
}

// ---- i8 GEMM: 4 waves x 128x128, 4-buffer distance-3 DMA, frag dbuf ----
__device__ __forceinline__ void dma16(const uint8_t* g, uint8_t* l) {
  __builtin_amdgcn_global_load_lds(
      (const __attribute__((address_space(1))) uint32_t*)g,
      (__attribute__((address_space(3))) uint32_t*)l, 16, 0, 0);
}

__global__ __launch_bounds__(256, 1) void gemm_i8_sq(
    const uint8_t* __restrict__ wsa, const uint8_t* __restrict__ wsb,
    const float* __restrict__ sx, const float* __restrict__ sw,
    float* __restrict__ out)
{
  __shared__ __align__(16) uint8_t sA[4 * CHUNK2];   // 64 KB
  __shared__ __align__(16) uint8_t sB[4 * CHUNK2];   // 64 KB

  const int tid  = threadIdx.x;
  const int lane = tid & 63;
  const int wv   = tid >> 6;           // 4 waves, 2(M) x 2(N)
  const int wm   = wv >> 1, wn = wv & 1;
  const int h    = lane >> 5;          // k-half of the 32x32x32 MFMA
  const int ml   = lane & 31;

  // bijective XCD swizzle: each XCD gets 86 consecutive slots => whole
  // qq-panels stream through one XCD's L2.
  const int lin = blockIdx.y * A_PANELS2 + blockIdx.x;   // dispatch order
  const int swz = (lin & 7) * CPX2 + (lin >> 3);
  const int pp  = swz & (A_PANELS2 - 1);
  const int qq  = swz >> 4;

  const uint8_t* chunkA = wsa + (size_t)pp * STAGES * CHUNK2;
  const uint8_t* chunkB = wsb + (size_t)qq * STAGES * CHUNK2;

  // DMA split: waves 0,1 -> A halves; waves 2,3 -> B halves. 8 insts/wave.
  const uint8_t* gsrc = (wv < 2) ? chunkA : chunkB;
  uint8_t* lbase      = (wv < 2) ? sA : sB;
  const int half      = (wv & 1) * 8192;

  auto dma_stage = [&](int s) {
    const int buf = s & 3;
    const uint8_t* g = gsrc + (size_t)s * CHUNK2 + half + lane * 16;
    uint8_t* l = lbase + buf * CHUNK2 + half;
#pragma unroll
    for (int i = 0; i < 8; ++i) dma16(g + i * 1024, l + i * 1024);
  };

  const int rowA = (wm * 128 + ml) * 16;      // byte offset inside a cell
  const int rowB = (wn * 128 + ml) * 16;

  int32x16 acc[4][4];
#pragma unroll
  for (int mi = 0; mi < 4; ++mi)
#pragma unroll
    for (int ni = 0; ni < 4; ++ni)
#pragma unroll
      for (int i = 0; i < 16; ++i) acc[mi][ni][i] = 0;

  // prologue: stages 0,1,2 in flight (24 insts/wave, 8 per stage, in order)
  dma_stage(0); dma_stage(1); dma_stage(2);
  asm volatile("s_waitcnt vmcnt(16)" ::: "memory");   // DMA(0) complete
  __builtin_amdgcn_s_barrier();

  int32x4 a0[4], b0[4];
  {                                   // preload stage-0 k-step-0 fragments
    const uint8_t* pa = sA + h * 4096 + rowA;
    const uint8_t* pb = sB + h * 4096 + rowB;
#pragma unroll
    for (int i = 0; i < 4; ++i) a0[i] = *(const int32x4*)(pa + i * 512);
#pragma unroll
    for (int i = 0; i < 4; ++i) b0[i] = *(const int32x4*)(pb + i * 512);
  }

#pragma unroll 1
  for (int s = 0; s < STAGES; ++s) {
    const int rb = s & 3;
    // Steady state: outstanding = DMA(s+1),DMA(s+2) (16). vmcnt(8) drains
    // DMA(s+1) => bufs s and s+1 are both readable. s>=62: drain all.
    if (s < STAGES - 2) asm volatile("s_waitcnt vmcnt(8)" ::: "memory");
    else                asm volatile("s_waitcnt vmcnt(0)" ::: "memory");
    __builtin_amdgcn_s_barrier();
    if (s + 3 < STAGES) dma_stage(s + 3);   // writes buf (s+3)&3 == (s-1)&3

    const uint8_t* baseA = sA + rb * CHUNK2;
    const uint8_t* baseB = sB + rb * CHUNK2;

    // k-step-1 fragments (cells 2..3) of current stage
    int32x4 a1[4], b1[4];
    {
      const uint8_t* pa = baseA + (2 + h) * 4096 + rowA;
      const uint8_t* pb = baseB + (2 + h) * 4096 + rowB;
#pragma unroll
      for (int i = 0; i < 4; ++i) a1[i] = *(const int32x4*)(pa + i * 512);
#pragma unroll
      for (int i = 0; i < 4; ++i) b1[i] = *(const int32x4*)(pb + i * 512);
    }

    // k-step-0 MFMAs: operands preloaded last stage -> no post-barrier stall
    __builtin_amdgcn_s_setprio(1);
#pragma unroll
    for (int mi = 0; mi < 4; ++mi)
#pragma unroll
      for (int ni = 0; ni < 4; ++ni)
        acc[mi][ni] = __builtin_amdgcn_mfma_i32_32x32x32_i8(
            a0[mi], b0[ni], acc[mi][ni], 0, 0, 0);
    __builtin_amdgcn_s_setprio(0);

    // preload next stage's k-step-0 fragments from buf (s+1)&3.
    // Safe: DMA(s+1) drained at this stage's top; that buffer's next writer
    // is DMA(s+5), issued two barriers later; our reads retire (lgkm) before
    // their use next stage, which precedes that barrier.
    if (s + 1 < STAGES) {
      const int nb = (s + 1) & 3;
      const uint8_t* pa = sA + nb * CHUNK2 + h * 4096 + rowA;
      const uint8_t* pb = sB + nb * CHUNK2 + h * 4096 + rowB;
#pragma unroll
      for (int i = 0; i < 4; ++i) a0[i] = *(const int32x4*)(pa + i * 512);
#pragma unroll
      for (int i = 0; i < 4; ++i) b0[i] = *(const int32x4*)(pb + i * 512);
    }

    // k-step-1 MFMAs
    __builtin_amdgcn_s_setprio(1);
#pragma unroll
    for (int mi = 0; mi < 4; ++mi)
#pragma unroll
      for (int ni = 0; ni < 4; ++ni)
        acc[mi][ni] = __builtin_amdgcn_mfma_i32_32x32x32_i8(
            a1[mi], b1[ni], acc[mi][ni], 0, 0, 0);
    __builtin_amdgcn_s_setprio(0);
  }

  // epilogue: C/D (verified): col = lane&31, row = (reg&3) + 8*(reg>>2) + 4*(lane>>5)
#pragma unroll
  for (int mi = 0; mi < 4; ++mi) {
    const int rbase = pp * BM2 + wm * 128 + mi * 32 + 4 * h;
    float sxv[16];
#pragma unroll
    for (int r = 0; r < 16; ++r) sxv[r] = sx[rbase + (r & 3) + 8 * (r >> 2)];
#pragma unroll
    for (int ni = 0; ni < 4; ++ni) {
      const int gcol = qq * BN2 + wn * 128 + ni * 32 + ml;
      const float swv = sw[gcol];
#pragma unroll
      for (int r = 0; r < 16; ++r) {
        const int grow = rbase + (r & 3) + 8 * (r >> 2);
        const float v = (float)acc[mi][ni][r] * sxv[r] * swv;  // ref mul order
        out[(size_t)grow * N_DIM + gcol] = __half2float(__float2half(v));
      }
    }
  }
}

// ================= fallback (round-3, proven): f16 MFMA paths =================
__global__ __launch_bounds__(256) void repack_int32_to_bytes(
    const int* __restrict__ xa, const int* __restrict__ xw,
    uint32_t* __restrict__ da, uint32_t* __restrict__ dw)
{
  const size_t i = (size_t)blockIdx.x * blockDim.x + threadIdx.x;
  const size_t na4 = NA_BYTES / 4;
  const int4* src; uint32_t* dst; size_t off;
  if (i < na4) { src = (const int4*)xa; dst = da; off = i; }
  else         { src = (const int4*)xw; dst = dw; off = i - na4; }
  const int4 v = src[off];
  dst[off] = pack4(v);
}

__device__ __forceinline__ uint32_t cvt2(uint32_t m) {
  union U { uint32_t u; f16x2 h; } a, b, c;
  a.u = m ^ 0x64086408u; b.u = 0xE408E408u; c.h = a.h + b.h;
  return c.u;
}
__device__ __forceinline__ void unpack_cell(uint32_t* cell, uint32_t p) {
  cell[0] = cvt2( p        & 0x000F000Fu);
  cell[1] = cvt2((p >> 4)  & 0x000F000Fu);
  cell[2] = cvt2((p >> 8)  & 0x000F000Fu);
  cell[3] = cvt2((p >> 12) & 0x000F000Fu);
}

template <bool PACKED>
__global__ __launch_bounds__(256) void linear4bit_f16(
    const uint8_t* __restrict__ pqx, const float* __restrict__ sx,
    const uint8_t* __restrict__ wq,  const float* __restrict__ sw,
    const int* __restrict__ pqx32,   const int* __restrict__ wq32,
    float* __restrict__ out)
{
  __shared__ uint32_t sAf[8][128][4];
  __shared__ uint32_t sBf[8][128][4];
  const int tid = threadIdx.x, lane = tid & 63, wv = tid >> 6;
  const int wm = wv >> 1, wn = wv & 1, qd = lane >> 4, m16 = lane & 15;
  const int bm0 = blockIdx.x * 128, bn0 = blockIdx.y * 128;
  const int srow = tid >> 1, sh = tid & 1;
  const uint8_t* aPtr = pqx + (size_t)(bm0 + srow) * KP + sh * 16;
  const uint8_t* bPtr = wq  + (size_t)(bn0 + srow) * KP + sh * 16;
  const int* aPtr32 = pqx32 + (size_t)(bm0 + srow) * KP + sh * 16;
  const int* bPtr32 = wq32  + (size_t)(bn0 + srow) * KP + sh * 16;
  floatx4 acc[4][4];
#pragma unroll
  for (int mi = 0; mi < 4; ++mi)
#pragma unroll
    for (int ni = 0; ni < 4; ++ni)
#pragma unroll
      for (int r = 0; r < 4; ++r) acc[mi][ni][r] = 0.0f;
  uint4 ar, br;
  auto load_stage = [&](int s) {
    if (PACKED) {
      ar = *(const uint4*)(aPtr + (size_t)s * 32);
      br = *(const uint4*)(bPtr + (size_t)s * 32);
    } else {
      const int4* a4 = (const int4*)(aPtr32 + (size_t)s * 32);
      const int4* b4 = (const int4*)(bPtr32 + (size_t)s * 32);
      ar.x = pack4(a4[0]); ar.y = pack4(a4[1]); ar.z = pack4(a4[2]); ar.w = pack4(a4[3]);
      br.x = pack4(b4[0]); br.y = pack4(b4[1]); br.z = pack4(b4[2]); br.w = pack4(b4[3]);
    }
  };
  auto stage_to_lds = [&]() {
    uint32_t pa[4] = {ar.x, ar.y, ar.z, ar.w};
    uint32_t pb[4] = {br.x, br.y, br.z, br.w};
#pragma unroll
    for (int i = 0; i < 4; ++i) {
      unpack_cell(&sAf[4 * sh + i][srow][0], pa[i]);
      unpack_cell(&sBf[4 * sh + i][srow][0], pb[i]);
    }
  };
  load_stage(0); stage_to_lds();
#pragma unroll 1
  for (int s = 0; s < STAGES; ++s) {
    __syncthreads();
    if (s + 1 < STAGES) load_stage(s + 1);
#pragma unroll
    for (int s2 = 0; s2 < 2; ++s2) {
      f16x8 aF[4], bF[4];
#pragma unroll
      for (int mi = 0; mi < 4; ++mi)
        aF[mi] = *(const f16x8*)&sAf[4 * s2 + qd][wm * 64 + mi * 16 + m16][0];
#pragma unroll
      for (int ni = 0; ni < 4; ++ni)
        bF[ni] = *(const f16x8*)&sBf[4 * s2 + qd][wn * 64 + ni * 16 + m16][0];
#pragma unroll
      for (int mi = 0; mi < 4; ++mi)
#pragma unroll
        for (int ni = 0; ni < 4; ++ni)
          acc[mi][ni] = __builtin_amdgcn_mfma_f32_16x16x32_f16(aF[mi], bF[ni], acc[mi][ni], 0, 0, 0);
    }
    __syncthreads();
    if (s + 1 < STAGES) stage_to_lds();
  }
#pragma unroll
  for (int mi = 0; mi < 4; ++mi) {
    const int grow0 = bm0 + wm * 64 + mi * 16 + qd * 4;
    const float s0 = sx[grow0], s1 = sx[grow0 + 1], s2v = sx[grow0 + 2], s3 = sx[grow0 + 3];
#pragma unroll
    for (int ni = 0; ni < 4; ++ni) {
      const int gcol = bn0 + wn * 64 + ni * 16 + m16;
      const float swv = sw[gcol];
      const floatx4 a = acc[mi][ni];
      out[(size_t)(grow0 + 0) * N_DIM + gcol] = __half2float(__float2half(a[0] * s0 * swv));
      out[(size_t)(grow0 + 1) * N_DIM + gcol] = __half2float(__float2half(a[1] * s1 * swv));
      out[(size_t)(grow0 + 2) * N_DIM + gcol] = __half2float(__float2half(a[2] * s2v * swv));
      out[(size_t)(grow0 + 3) * N_DIM + gcol] = __half2float(__float2half(a[3] * s3 * swv));
    }
  }
}

extern "C" void kernel_launch(void* const* d_in, const int* in_sizes, int n_in,
                              void* d_out, int out_size, void* d_ws, size_t ws_size,
                              hipStream_t stream) {
  const int*   pqx32 = (const int*)d_in[0];   // [4096*2048] int32 (one per packed byte)
  const float* sxp   = (const float*)d_in[1]; // [4096]
  const int*   wq32  = (const int*)d_in[2];   // [11008*2048] int32
  const float* swp   = (const float*)d_in[3]; // [11008]
  float* outp = (float*)d_out;                // [4096, 11008] fp32 (fp16-rounded)

  if (ws_size >= WS_A + WS_B) {
    uint8_t* wsa = (uint8_t*)d_ws;
    uint8_t* wsb = wsa + WS_A;
    unpack_tiles4<<<dim3(STAGES / SGRP, T_DIM / ROWS_PB + N_DIM / ROWS_PB), 256, 0, stream>>>(
        pqx32, wq32, wsa, wsb);
    gemm_i8_sq<<<dim3(A_PANELS2, B_PANELS2), 256, 0, stream>>>(wsa, wsb, sxp, swp, outp);
  } else if (ws_size >= NA_BYTES + NW_BYTES) {
    uint8_t* da = (uint8_t*)d_ws;
    uint8_t* dw = da + NA_BYTES;
    const size_t total4 = (NA_BYTES + NW_BYTES) / 4;
    repack_int32_to_bytes<<<(uint32_t)(total4 / 256), 256, 0, stream>>>(
        pqx32, wq32, (uint32_t*)da, (uint32_t*)dw);
    linear4bit_f16<true><<<dim3(T_DIM / 128, N_DIM / 128), 256, 0, stream>>>(
        da, sxp, dw, swp, nullptr, nullptr, outp);
  } else {
    linear4bit_f16<false><<<dim3(T_DIM / 128, N_DIM / 128), 256, 0, stream>>>(
        nullptr, sxp, nullptr, swp, pqx32, wq32, outp);
  }
}

// Round 4
// 630.952 us; speedup vs baseline: 1.1829x; 1.1829x over previous
//
#include <hip/hip_runtime.h>
#include <hip/hip_fp16.h>
#include <stdint.h>

// Linear4bit: out[t,n] = (sum_k a4[t,k]*w4[n,k]) * sx[t] * sw[n], fp16-rounded.
// Inputs arrive int32-widened: one int32 per *packed byte* (two nibbles).
// Round-10: FUSED single kernel. R3's square tile spilled (VGPR 256 + 1.68GB
// scratch-eviction WRITE_SIZE) -> reverted to R1's proven MFMA core (128x256
// block, 8 waves of 64x64, [cell][row][16B] LDS, 226us). The ~230us residual
// is invariant across unpack implementations -> suspect two-kernel structure
// + 62MB workspace re-poison, not unpack speed. This round eliminates the
// preprocessing pass: reg-staged global->LDS with inline SWAR nibble->int8
// (VALU was only 15% busy), T14 issue-early/write-late, 2-deep LDS buffer,
// one __syncthreads per stage, bijective XCD swizzle. No workspace use at all.

#define T_DIM 4096
#define K_DIM 4096
#define N_DIM 11008
#define KP    2048              // packed bytes (= int32 elements) per row
#define BM 128
#define BN 256
#define STAGES 64               // BK = 64 (32 packed bytes per row per stage)
#define A_PANELS (T_DIM / BM)   // 32
#define B_PANELS (N_DIM / BN)   // 43
#define NWG (A_PANELS * B_PANELS)   // 1376, divisible by 8
#define CPX (NWG / 8)               // 172 blocks per XCD

typedef __attribute__((ext_vector_type(4)))  int int32x4;
typedef __attribute__((ext_vector_type(16))) int int32x16;

__device__ __forceinline__ uint32_t pack4(int4 v) {
  return (uint32_t)(v.x & 0xFF) | ((uint32_t)(v.y & 0xFF) << 8) |
         ((uint32_t)(v.z & 0xFF) << 16) | ((uint32_t)(v.w & 0xFF) << 24);
}
// borrow-free SWAR nibble -> signed int8
__device__ __forceinline__ uint32_t nib_lo_s8(uint32_t p) {
  uint32_t t = (p & 0x0F0F0F0Fu) ^ 0x88888888u;
  return (t - 0x08080808u) ^ 0x80808080u;
}
__device__ __forceinline__ uint32_t nib_hi_s8(uint32_t p) {
  uint32_t t = ((p >> 4) & 0x0F0F0F0Fu) ^ 0x88888888u;
  return (t - 0x08080808u) ^ 0x80808080u;
}
// 4 packed bytes (as 4 int32) -> {lo-nibble dword, hi-nibble dword} of int8
__device__ __forceinline__ uint2 nib2(int4 v) {
  const uint32_t p = pack4(v);
  return make_uint2(nib_lo_s8(p), nib_hi_s8(p));
}

// Cell layout (proven rounds 0-2): stage = 4 cells of 16 int8 per row.
// Cell c covers packed bytes [8c, 8c+8): dwords [lo(0-3), hi(0-3), lo(4-7),
// hi(4-7)]. Identical construction for A and B => MFMA k-order consistent.

__global__ __launch_bounds__(512, 2) void gemm_i8_fused(
    const int* __restrict__ xa, const int* __restrict__ xw,
    const float* __restrict__ sx, const float* __restrict__ sw,
    float* __restrict__ out)
{
  __shared__ __align__(16) uint8_t sA[2 * 8192];    // 2 x [4 cells][128][16B]
  __shared__ __align__(16) uint8_t sB[2 * 16384];   // 2 x [4 cells][256][16B]

  const int tid  = threadIdx.x;
  const int lane = tid & 63;
  const int wv   = tid >> 6;           // 8 waves, 2(M) x 4(N)
  const int wm   = wv >> 2, wn = wv & 3;
  const int h    = lane >> 5;          // k-half of the 32x32x32 MFMA
  const int ml   = lane & 31;

  // bijective XCD swizzle: 32 consecutive slots per XCD share one B panel.
  const int lin = blockIdx.y * A_PANELS + blockIdx.x;   // 0..1375
  const int swz = (lin & 7) * CPX + (lin >> 3);
  const int pp  = swz & (A_PANELS - 1);
  const int qq  = swz >> 5;            // 0..42
  const int bm0 = pp * BM, bn0 = qq * BN;

  // ---- staging task shape: j = pb-quad 0..7 (global-contiguous in lane),
  //      r0 = row 0..63; A covers rows r0,r0+64; B rows r0+64i, i=0..3.
  const int jj = tid & 7;
  const int r0 = tid >> 3;             // 0..63
  const int* gA = xa + (size_t)(bm0 + r0) * KP + jj * 4;
  const int* gB = xw + (size_t)(bn0 + r0) * KP + jj * 4;

  int4 rA[2], rB[4];                   // raw staging regs (24 VGPRs)
  auto issue = [&](int s) {
    const int o = s * 32;
    rA[0] = *(const int4*)(gA + o);
    rA[1] = *(const int4*)(gA + o + 64 * KP);
#pragma unroll
    for (int i = 0; i < 4; ++i)
      rB[i] = *(const int4*)(gB + o + (size_t)i * 64 * KP);
  };

  // LDS write target: cell = jj>>1, dword-pair = jj&1, row = r0 (+64i)
  uint8_t* const wA0 = sA + (jj >> 1) * 2048 + r0 * 16 + (jj & 1) * 8;
  uint8_t* const wB0 = sB + (jj >> 1) * 4096 + r0 * 16 + (jj & 1) * 8;
  auto stash = [&](int buf) {
    uint8_t* wa = wA0 + buf * 8192;
    uint8_t* wb = wB0 + buf * 16384;
    *(uint2*)(wa)        = nib2(rA[0]);
    *(uint2*)(wa + 1024) = nib2(rA[1]);            // +64 rows
#pragma unroll
    for (int i = 0; i < 4; ++i)
      *(uint2*)(wb + i * 1024) = nib2(rB[i]);
  };

  const int rowA = (wm * 64 + ml) * 16;   // byte offset inside a cell
  const int rowB = (wn * 64 + ml) * 16;

  int32x16 acc[2][2];
#pragma unroll
  for (int mi = 0; mi < 2; ++mi)
#pragma unroll
    for (int ni = 0; ni < 2; ++ni)
#pragma unroll
      for (int i = 0; i < 16; ++i) acc[mi][ni][i] = 0;

  // prologue: stage 0 loaded, transformed, written to buf 0
  issue(0);
  stash(0);
  __syncthreads();

#pragma unroll 1
  for (int s = 0; s < STAGES; ++s) {
    const int rb = s & 1;
    if (s + 1 < STAGES) issue(s + 1);       // loads hide under MFMA below

    const uint8_t* baseA = sA + rb * 8192;
    const uint8_t* baseB = sB + rb * 16384;
#pragma unroll
    for (int s2 = 0; s2 < 2; ++s2) {        // two K=32 MFMA steps
      const int c = 2 * s2 + h;
      const uint8_t* pa = baseA + c * 2048 + rowA;
      const uint8_t* pb = baseB + c * 4096 + rowB;
      int32x4 aF[2], bF[2];
#pragma unroll
      for (int mi = 0; mi < 2; ++mi) aF[mi] = *(const int32x4*)(pa + mi * 512);
#pragma unroll
      for (int ni = 0; ni < 2; ++ni) bF[ni] = *(const int32x4*)(pb + ni * 512);
      __builtin_amdgcn_s_setprio(1);
#pragma unroll
      for (int mi = 0; mi < 2; ++mi)
#pragma unroll
        for (int ni = 0; ni < 2; ++ni)
          acc[mi][ni] = __builtin_amdgcn_mfma_i32_32x32x32_i8(
              aF[mi], bF[ni], acc[mi][ni], 0, 0, 0);
      __builtin_amdgcn_s_setprio(0);
    }

    if (s + 1 < STAGES) {
      // raw regs ready by now (issued one full MFMA phase ago); transform and
      // write buf rb^1 (its readers finished at stage s-1, separated by the
      // barrier below from last iteration). Barrier orders these writes
      // before stage s+1's reads.
      stash(rb ^ 1);
      __syncthreads();
    }
  }

  // epilogue: C/D (verified): col = lane&31, row = (reg&3) + 8*(reg>>2) + 4*(lane>>5)
#pragma unroll
  for (int mi = 0; mi < 2; ++mi) {
    const int rbase = bm0 + wm * 64 + mi * 32 + 4 * h;
    float sxv[16];
#pragma unroll
    for (int r = 0; r < 16; ++r) sxv[r] = sx[rbase + (r & 3) + 8 * (r >> 2)];
#pragma unroll
    for (int ni = 0; ni < 2; ++ni) {
      const int gcol = bn0 + wn * 64 + ni * 32 + ml;
      const float swv = sw[gcol];
#pragma unroll
      for (int r = 0; r < 16; ++r) {
        const int grow = rbase + (r & 3) + 8 * (r >> 2);
        const float v = (float)acc[mi][ni][r] * sxv[r] * swv;  // ref mul order
        out[(size_t)grow * N_DIM + gcol] = __half2float(__float2half(v));
      }
    }
  }
}

extern "C" void kernel_launch(void* const* d_in, const int* in_sizes, int n_in,
                              void* d_out, int out_size, void* d_ws, size_t ws_size,
                              hipStream_t stream) {
  const int*   pqx32 = (const int*)d_in[0];   // [4096*2048] int32 (one per packed byte)
  const float* sxp   = (const float*)d_in[1]; // [4096]
  const int*   wq32  = (const int*)d_in[2];   // [11008*2048] int32
  const float* swp   = (const float*)d_in[3]; // [11008]
  float* outp = (float*)d_out;                // [4096, 11008] fp32 (fp16-rounded)

  (void)d_ws; (void)ws_size;                  // workspace intentionally unused
  gemm_i8_fused<<<dim3(A_PANELS, B_PANELS), 512, 0, stream>>>(
      pqx32, wq32, sxp, swp, outp);
}

// Round 5
// 509.066 us; speedup vs baseline: 1.4661x; 1.2394x over previous
//
#include <hip/hip_runtime.h>
#include <hip/hip_fp16.h>
#include <stdint.h>

// Linear4bit: out[t,n] = (sum_k a4[t,k]*w4[n,k]) * sx[t] * sw[n], fp16-rounded.
// Inputs arrive int32-widened: one int32 per *packed byte* (two nibbles).
// Round-11: back to the proven two-kernel structure (R4 fusion refuted:
// 4x input footprint -> 538MB FETCH, ds_write bank conflicts 5e7). GEMM
// scaled to 256x256 / 8 waves of 128x64 (halves staging bytes per MFMA),
// keeping R1's exact sync scheme: 3-buffer distance-2 global_load_lds,
// counted vmcnt(4) (4 DMA/wave/stage), raw s_barrier, setprio around MFMA.
// Workspace layout: 256-row panels (unpack_tiles4, proven in R3).
// Register budget: acc[4][2]=128 + frags 24 + addr ~30 => no spill at
// 2 waves/SIMD (1 block/CU, LDS 96KB). Tripwires: VGPR!=256, WRITE==176MB.

#define T_DIM 4096
#define K_DIM 4096
#define N_DIM 11008
#define KP    2048              // packed bytes (= int32 elements) per row
#define STAGES 64               // BK = 64 (32 packed bytes per row per stage)
#define BM2 256
#define BN2 256
#define CHUNK2 16384            // 4 cells x 256 rows x 16B (A and B identical)
#define A_PANELS2 (T_DIM / BM2)   // 16
#define B_PANELS2 (N_DIM / BN2)   // 43
#define NWG2 (A_PANELS2 * B_PANELS2)      // 688, divisible by 8
#define CPX2 (NWG2 / 8)                   // 86 blocks per XCD
#define WS_A ((size_t)A_PANELS2 * STAGES * CHUNK2)   // 16,777,216
#define WS_B ((size_t)B_PANELS2 * STAGES * CHUNK2)   // 45,088,768
#define NA_BYTES ((size_t)T_DIM * KP)                // fallback packed sizes
#define NW_BYTES ((size_t)N_DIM * KP)

typedef __attribute__((ext_vector_type(4)))  int int32x4;
typedef __attribute__((ext_vector_type(16))) int int32x16;
typedef __attribute__((ext_vector_type(4)))  float floatx4;
typedef __attribute__((ext_vector_type(8)))  _Float16 f16x8;
typedef __attribute__((ext_vector_type(2)))  _Float16 f16x2;

__device__ __forceinline__ uint32_t pack4(int4 v) {
  return (uint32_t)(v.x & 0xFF) | ((uint32_t)(v.y & 0xFF) << 8) |
         ((uint32_t)(v.z & 0xFF) << 16) | ((uint32_t)(v.w & 0xFF) << 24);
}
// borrow-free SWAR nibble -> signed int8
__device__ __forceinline__ uint32_t nib_lo_s8(uint32_t p) {
  uint32_t t = (p & 0x0F0F0F0Fu) ^ 0x88888888u;
  return (t - 0x08080808u) ^ 0x80808080u;
}
__device__ __forceinline__ uint32_t nib_hi_s8(uint32_t p) {
  uint32_t t = ((p >> 4) & 0x0F0F0F0Fu) ^ 0x88888888u;
  return (t - 0x08080808u) ^ 0x80808080u;
}

// ------------- preprocess v4 (proven R3): coalesced loads + LDS transpose ----
#define ROWS_PB 32
#define SGRP    16

__global__ __launch_bounds__(256) void unpack_tiles4(
    const int* __restrict__ xa, const int* __restrict__ xw,
    uint8_t* __restrict__ wsa, uint8_t* __restrict__ wsb)
{
  __shared__ __align__(16) uint32_t lds[8192];   // 32 KB
  const int sg  = blockIdx.x;        // stage group 0..3 (16 stages each)
  const int yb  = blockIdx.y;        // A: [0,128)  B: [128,472)
  const int tid = threadIdx.x;

  const int* srcBase; uint8_t* dstBase;
  if (yb < T_DIM / ROWS_PB) {
    srcBase = xa + (size_t)yb * ROWS_PB * KP + sg * SGRP * 32;
    dstBase = wsa + ((size_t)(yb >> 3) * STAGES + sg * SGRP) * CHUNK2
                  + (size_t)(yb & 7) * (ROWS_PB * 16);
  } else {
    const int zb = yb - T_DIM / ROWS_PB;         // 0..343
    srcBase = xw + (size_t)zb * ROWS_PB * KP + sg * SGRP * 32;
    dstBase = wsb + ((size_t)(zb >> 3) * STAGES + sg * SGRP) * CHUNK2
                  + (size_t)(zb & 7) * (ROWS_PB * 16);
  }

  // ---- phase 1: global (coalesced) -> LDS (swizzled) ----
  const int lq    = tid & 127;       // 128 threads cover one 2KB row-slice
  const int rhalf = tid >> 7;        // which of the 2 rows per iteration
  const int sl    = lq >> 3;         // stage-local 0..15
  const int tg    = lq & 7;          // byte-group 0..7 (4 packed bytes each)
  const int cellL = (tg & 1) * 2;
  const int dsl   = tg >> 1;         // dword slot 0..3
#pragma unroll
  for (int it = 0; it < 16; ++it) {
    const int row = it * 2 + rhalf;
    const int4 v = *(const int4*)(srcBase + (size_t)row * KP + lq * 4);
    const uint32_t p = pack4(v);
    const int sp = sl ^ (row & 7);
    uint32_t* b = &lds[(((cellL * 32 + row) << 4) + sp) * 4 + dsl];
    b[0]    = nib_lo_s8(p);          // cell cellL
    b[2048] = nib_hi_s8(p);          // cell cellL+1  (+32*16*4 dwords)
  }
  __syncthreads();

  // ---- phase 2: LDS -> workspace, 512B contiguous runs per half-wave ----
  const int row2 = tid & 31;
#pragma unroll
  for (int it = 0; it < 8; ++it) {
    const int pr = it * 8 + (tid >> 5);          // 0..63 = (stage,cell) pair
    const int s2 = pr >> 2, cl = pr & 3;
    const int sp = s2 ^ (row2 & 7);
    const uint4 v = *(const uint4*)&lds[(((cl * 32 + row2) << 4) + sp) * 4];
    *(uint4*)(dstBase + (size_t)s2 * CHUNK2 + cl * 4096 + row2 * 16) = v;
  }
}

// ---- i8 GEMM: 8 waves x 128x64, 3-buffer distance-2 DMA, counted vmcnt ----
__device__ __forceinline__ void dma16(const uint8_t* g, uint8_t* l) {
  __builtin_amdgcn_global_load_lds(
      (const __attribute__((address_space(1))) uint32_t*)g,
      (__attribute__((address_space(3))) uint32_t*)l, 16, 0, 0);
}

__global__ __launch_bounds__(512) void gemm_i8_sq2(
    const uint8_t* __restrict__ wsa, const uint8_t* __restrict__ wsb,
    const float* __restrict__ sx, const float* __restrict__ sw,
    float* __restrict__ out)
{
  __shared__ __align__(16) uint8_t sA[3 * CHUNK2];   // 48 KB
  __shared__ __align__(16) uint8_t sB[3 * CHUNK2];   // 48 KB

  const int tid  = threadIdx.x;
  const int lane = tid & 63;
  const int wv   = tid >> 6;           // 8 waves, 2(M) x 4(N)
  const int wm   = wv >> 2, wn = wv & 3;
  const int h    = lane >> 5;          // k-half of the 32x32x32 MFMA
  const int ml   = lane & 31;

  // bijective XCD swizzle: 86 consecutive slots per XCD; qq constant in
  // runs of 16 => one 1MB B-panel hot per XCD-L2 window.
  const int lin = blockIdx.y * A_PANELS2 + blockIdx.x;   // 0..687
  const int swz = (lin & 7) * CPX2 + (lin >> 3);
  const int pp  = swz & (A_PANELS2 - 1);
  const int qq  = swz >> 4;            // 0..42

  const uint8_t* chunkA = wsa + (size_t)pp * STAGES * CHUNK2;
  const uint8_t* chunkB = wsb + (size_t)qq * STAGES * CHUNK2;
  const int segOff = wv * 1024 + lane * 16;   // per-lane global offset
  const int ldsOff = wv * 1024;               // wave-uniform LDS base

  // Exactly 4 global_load_lds per wave per stage — vmcnt bookkeeping exact.
  auto dma_stage = [&](int s, int buf) {
    const uint8_t* ga = chunkA + (size_t)s * CHUNK2 + segOff;
    const uint8_t* gb = chunkB + (size_t)s * CHUNK2 + segOff;
    uint8_t* la = sA + buf * CHUNK2 + ldsOff;
    uint8_t* lb = sB + buf * CHUNK2 + ldsOff;
    dma16(ga,        la);
    dma16(ga + 8192, la + 8192);
    dma16(gb,        lb);
    dma16(gb + 8192, lb + 8192);
  };

  const int rowA = (wm * 128 + ml) * 16;      // byte offset inside a cell
  const int rowB = (wn * 64 + ml) * 16;

  int32x16 acc[4][2];
#pragma unroll
  for (int mi = 0; mi < 4; ++mi)
#pragma unroll
    for (int ni = 0; ni < 2; ++ni)
#pragma unroll
      for (int i = 0; i < 16; ++i) acc[mi][ni][i] = 0;

  dma_stage(0, 0);                     // prologue: stages 0,1 in flight (8)
  dma_stage(1, 1);

  int rb = 0;                          // read buffer  = s % 3
  int wb = 2;                          // write buffer = (s+2) % 3
#pragma unroll 1
  for (int s = 0; s < STAGES; ++s) {
    // Drain DMA(s) only; keep DMA(s+1) (4 newest) in flight across barrier.
    if (s < STAGES - 1) asm volatile("s_waitcnt vmcnt(4)" ::: "memory");
    else                asm volatile("s_waitcnt vmcnt(0)" ::: "memory");
    __builtin_amdgcn_s_barrier();      // raw barrier: no compiler vmcnt(0) drain
    // Safe: buffer wb was last read at stage s-1; all waves passed the barrier
    // above, so those ds_reads (consumed by MFMAs before it) are complete.
    if (s + 2 < STAGES) dma_stage(s + 2, wb);

    const uint8_t* baseA = sA + rb * CHUNK2;
    const uint8_t* baseB = sB + rb * CHUNK2;
#pragma unroll
    for (int s2 = 0; s2 < 2; ++s2) {   // two K=32 MFMA steps
      const int c = 2 * s2 + h;
      const uint8_t* pa = baseA + c * 4096 + rowA;
      const uint8_t* pb = baseB + c * 4096 + rowB;
      int32x4 aF[4], bF[2];
#pragma unroll
      for (int mi = 0; mi < 4; ++mi) aF[mi] = *(const int32x4*)(pa + mi * 512);
#pragma unroll
      for (int ni = 0; ni < 2; ++ni) bF[ni] = *(const int32x4*)(pb + ni * 512);
      __builtin_amdgcn_s_setprio(1);
#pragma unroll
      for (int mi = 0; mi < 4; ++mi)
#pragma unroll
        for (int ni = 0; ni < 2; ++ni)
          acc[mi][ni] = __builtin_amdgcn_mfma_i32_32x32x32_i8(
              aF[mi], bF[ni], acc[mi][ni], 0, 0, 0);
      __builtin_amdgcn_s_setprio(0);
    }
    rb = (rb == 2) ? 0 : rb + 1;       // rotate buffers
    wb = (wb == 2) ? 0 : wb + 1;
  }

  // epilogue: C/D (verified): col = lane&31, row = (reg&3) + 8*(reg>>2) + 4*(lane>>5)
#pragma unroll
  for (int mi = 0; mi < 4; ++mi) {
    const int rbase = pp * BM2 + wm * 128 + mi * 32 + 4 * h;
    float sxv[16];
#pragma unroll
    for (int r = 0; r < 16; ++r) sxv[r] = sx[rbase + (r & 3) + 8 * (r >> 2)];
#pragma unroll
    for (int ni = 0; ni < 2; ++ni) {
      const int gcol = qq * BN2 + wn * 64 + ni * 32 + ml;
      const float swv = sw[gcol];
#pragma unroll
      for (int r = 0; r < 16; ++r) {
        const int grow = rbase + (r & 3) + 8 * (r >> 2);
        const float v = (float)acc[mi][ni][r] * sxv[r] * swv;  // ref mul order
        out[(size_t)grow * N_DIM + gcol] = __half2float(__float2half(v));
      }
    }
  }
}

// ================= fallback (round-3, proven): f16 MFMA paths =================
__global__ __launch_bounds__(256) void repack_int32_to_bytes(
    const int* __restrict__ xa, const int* __restrict__ xw,
    uint32_t* __restrict__ da, uint32_t* __restrict__ dw)
{
  const size_t i = (size_t)blockIdx.x * blockDim.x + threadIdx.x;
  const size_t na4 = NA_BYTES / 4;
  const int4* src; uint32_t* dst; size_t off;
  if (i < na4) { src = (const int4*)xa; dst = da; off = i; }
  else         { src = (const int4*)xw; dst = dw; off = i - na4; }
  const int4 v = src[off];
  dst[off] = pack4(v);
}

__device__ __forceinline__ uint32_t cvt2(uint32_t m) {
  union U { uint32_t u; f16x2 h; } a, b, c;
  a.u = m ^ 0x64086408u; b.u = 0xE408E408u; c.h = a.h + b.h;
  return c.u;
}
__device__ __forceinline__ void unpack_cell(uint32_t* cell, uint32_t p) {
  cell[0] = cvt2( p        & 0x000F000Fu);
  cell[1] = cvt2((p >> 4)  & 0x000F000Fu);
  cell[2] = cvt2((p >> 8)  & 0x000F000Fu);
  cell[3] = cvt2((p >> 12) & 0x000F000Fu);
}

template <bool PACKED>
__global__ __launch_bounds__(256) void linear4bit_f16(
    const uint8_t* __restrict__ pqx, const float* __restrict__ sx,
    const uint8_t* __restrict__ wq,  const float* __restrict__ sw,
    const int* __restrict__ pqx32,   const int* __restrict__ wq32,
    float* __restrict__ out)
{
  __shared__ uint32_t sAf[8][128][4];
  __shared__ uint32_t sBf[8][128][4];
  const int tid = threadIdx.x, lane = tid & 63, wv = tid >> 6;
  const int wm = wv >> 1, wn = wv & 1, qd = lane >> 4, m16 = lane & 15;
  const int bm0 = blockIdx.x * 128, bn0 = blockIdx.y * 128;
  const int srow = tid >> 1, sh = tid & 1;
  const uint8_t* aPtr = pqx + (size_t)(bm0 + srow) * KP + sh * 16;
  const uint8_t* bPtr = wq  + (size_t)(bn0 + srow) * KP + sh * 16;
  const int* aPtr32 = pqx32 + (size_t)(bm0 + srow) * KP + sh * 16;
  const int* bPtr32 = wq32  + (size_t)(bn0 + srow) * KP + sh * 16;
  floatx4 acc[4][4];
#pragma unroll
  for (int mi = 0; mi < 4; ++mi)
#pragma unroll
    for (int ni = 0; ni < 4; ++ni)
#pragma unroll
      for (int r = 0; r < 4; ++r) acc[mi][ni][r] = 0.0f;
  uint4 ar, br;
  auto load_stage = [&](int s) {
    if (PACKED) {
      ar = *(const uint4*)(aPtr + (size_t)s * 32);
      br = *(const uint4*)(bPtr + (size_t)s * 32);
    } else {
      const int4* a4 = (const int4*)(aPtr32 + (size_t)s * 32);
      const int4* b4 = (const int4*)(bPtr32 + (size_t)s * 32);
      ar.x = pack4(a4[0]); ar.y = pack4(a4[1]); ar.z = pack4(a4[2]); ar.w = pack4(a4[3]);
      br.x = pack4(b4[0]); br.y = pack4(b4[1]); br.z = pack4(b4[2]); br.w = pack4(b4[3]);
    }
  };
  auto stage_to_lds = [&]() {
    uint32_t pa[4] = {ar.x, ar.y, ar.z, ar.w};
    uint32_t pb[4] = {br.x, br.y, br.z, br.w};
#pragma unroll
    for (int i = 0; i < 4; ++i) {
      unpack_cell(&sAf[4 * sh + i][srow][0], pa[i]);
      unpack_cell(&sBf[4 * sh + i][srow][0], pb[i]);
    }
  };
  load_stage(0); stage_to_lds();
#pragma unroll 1
  for (int s = 0; s < STAGES; ++s) {
    __syncthreads();
    if (s + 1 < STAGES) load_stage(s + 1);
#pragma unroll
    for (int s2 = 0; s2 < 2; ++s2) {
      f16x8 aF[4], bF[4];
#pragma unroll
      for (int mi = 0; mi < 4; ++mi)
        aF[mi] = *(const f16x8*)&sAf[4 * s2 + qd][wm * 64 + mi * 16 + m16][0];
#pragma unroll
      for (int ni = 0; ni < 4; ++ni)
        bF[ni] = *(const f16x8*)&sBf[4 * s2 + qd][wn * 64 + ni * 16 + m16][0];
#pragma unroll
      for (int mi = 0; mi < 4; ++mi)
#pragma unroll
        for (int ni = 0; ni < 4; ++ni)
          acc[mi][ni] = __builtin_amdgcn_mfma_f32_16x16x32_f16(aF[mi], bF[ni], acc[mi][ni], 0, 0, 0);
    }
    __syncthreads();
    if (s + 1 < STAGES) stage_to_lds();
  }
#pragma unroll
  for (int mi = 0; mi < 4; ++mi) {
    const int grow0 = bm0 + wm * 64 + mi * 16 + qd * 4;
    const float s0 = sx[grow0], s1 = sx[grow0 + 1], s2v = sx[grow0 + 2], s3 = sx[grow0 + 3];
#pragma unroll
    for (int ni = 0; ni < 4; ++ni) {
      const int gcol = bn0 + wn * 64 + ni * 16 + m16;
      const float swv = sw[gcol];
      const floatx4 a = acc[mi][ni];
      out[(size_t)(grow0 + 0) * N_DIM + gcol] = __half2float(__float2half(a[0] * s0 * swv));
      out[(size_t)(grow0 + 1) * N_DIM + gcol] = __half2float(__float2half(a[1] * s1 * swv));
      out[(size_t)(grow0 + 2) * N_DIM + gcol] = __half2float(__float2half(a[2] * s2v * swv));
      out[(size_t)(grow0 + 3) * N_DIM + gcol] = __half2float(__float2half(a[3] * s3 * swv));
    }
  }
}

extern "C" void kernel_launch(void* const* d_in, const int* in_sizes, int n_in,
                              void* d_out, int out_size, void* d_ws, size_t ws_size,
                              hipStream_t stream) {
  const int*   pqx32 = (const int*)d_in[0];   // [4096*2048] int32 (one per packed byte)
  const float* sxp   = (const float*)d_in[1]; // [4096]
  const int*   wq32  = (const int*)d_in[2];   // [11008*2048] int32
  const float* swp   = (const float*)d_in[3]; // [11008]
  float* outp = (float*)d_out;                // [4096, 11008] fp32 (fp16-rounded)

  if (ws_size >= WS_A + WS_B) {
    uint8_t* wsa = (uint8_t*)d_ws;
    uint8_t* wsb = wsa + WS_A;
    unpack_tiles4<<<dim3(STAGES / SGRP, T_DIM / ROWS_PB + N_DIM / ROWS_PB), 256, 0, stream>>>(
        pqx32, wq32, wsa, wsb);
    gemm_i8_sq2<<<dim3(A_PANELS2, B_PANELS2), 512, 0, stream>>>(wsa, wsb, sxp, swp, outp);
  } else if (ws_size >= NA_BYTES + NW_BYTES) {
    uint8_t* da = (uint8_t*)d_ws;
    uint8_t* dw = da + NA_BYTES;
    const size_t total4 = (NA_BYTES + NW_BYTES) / 4;
    repack_int32_to_bytes<<<(uint32_t)(total4 / 256), 256, 0, stream>>>(
        pqx32, wq32, (uint32_t*)da, (uint32_t*)dw);
    linear4bit_f16<true><<<dim3(T_DIM / 128, N_DIM / 128), 256, 0, stream>>>(
        da, sxp, dw, swp, nullptr, nullptr, outp);
  } else {
    linear4bit_f16<false><<<dim3(T_DIM / 128, N_DIM / 128), 256, 0, stream>>>(
        nullptr, sxp, nullptr, swp, pqx32, wq32, outp);
  }
}